// Round 13
// baseline (257.904 us; speedup 1.0000x reference)
//
#include <hip/hip_runtime.h>
#include <math.h>
#include <float.h>

#define T_ 384
#define D_ 512
#define H_ 8
#define HD_ 64
#define K_ 48
#define LN_EPS 1e-5f
#define NTOK 768
#define PSTRIDE (NTOK * D_)       // 393216 floats
#define T2 (T_ * T_)

// split-K completion counters, one per 32-row tile. Zero-init at module load;
// each launch adds exactly 32 per counter so (ret & 31)==31 marks the last
// arriver on every replay (wraps mod 2^32, 32 | 2^32).
__device__ unsigned g_ctr[24];

// ---------- k1: superposition per token (blocks 0..767) + M/Mb precompute
// (blocks 768..895). M = gate_w @ sp_w stored TRANSPOSED: MT[j][d] (64 x 512);
// Mb = gate_b + gate_w @ sp_b.
__global__ __launch_bounds__(256) void k_super_m(
    const float* __restrict__ x, const float* __restrict__ g_w,
    const float* __restrict__ g_b, const float* __restrict__ sp_w,
    const float* __restrict__ sp_b, const float* __restrict__ gate_w,
    const float* __restrict__ gate_b, float* __restrict__ xs,
    float* __restrict__ hd_g, float* __restrict__ MT, float* __restrict__ Mb) {
    __shared__ float xsh[D_];
    __shared__ float logits[H_];
    __shared__ float hdv[HD_];
    int bid = blockIdx.x, tid = threadIdx.x;
    if (bid < NTOK) {
        const float* xt = x + (size_t)bid * D_;
        ((float2*)xsh)[tid] = ((const float2*)xt)[tid];
        __syncthreads();
        int h = tid >> 5, l = tid & 31;
        float p = 0.f;
#pragma unroll
        for (int i = 0; i < 16; ++i) {
            int k = l + 32 * i;
            p += xsh[k] * g_w[h * D_ + k];
        }
#pragma unroll
        for (int off = 16; off > 0; off >>= 1) p += __shfl_xor(p, off);
        if (l == 0) logits[h] = p + g_b[h];
        __syncthreads();
        if (tid < HD_) {
            float m = logits[0];
#pragma unroll
            for (int hh = 1; hh < H_; ++hh) m = fmaxf(m, logits[hh]);
            float e[H_];
            float sum = 0.f;
#pragma unroll
            for (int hh = 0; hh < H_; ++hh) { e[hh] = expf(logits[hh] - m); sum += e[hh]; }
            float inv = 1.f / sum;
            float v = 0.f;
#pragma unroll
            for (int hh = 0; hh < H_; ++hh) v += e[hh] * inv * xsh[hh * HD_ + tid];
            hdv[tid] = v;
            hd_g[(size_t)bid * HD_ + tid] = v;
        }
        __syncthreads();
        float a0 = sp_b[tid], a1 = sp_b[tid + 256];
        const float* w0 = sp_w + (size_t)tid * HD_;
        const float* w1 = sp_w + (size_t)(tid + 256) * HD_;
#pragma unroll
        for (int k = 0; k < HD_; k += 4) {
            float4 h4 = *(const float4*)&hdv[k];
            float4 u0 = *(const float4*)&w0[k];
            float4 u1 = *(const float4*)&w1[k];
            a0 += h4.x * u0.x + h4.y * u0.y + h4.z * u0.z + h4.w * u0.w;
            a1 += h4.x * u1.x + h4.y * u1.y + h4.z * u1.z + h4.w * u1.w;
        }
        xs[(size_t)bid * D_ + tid] = a0;
        xs[(size_t)bid * D_ + 256 + tid] = a1;
    } else {
        // M/Mb block: 4 d-rows per block, thread = (r = tid>>6, l = tid&63)
        int d = (bid - NTOK) * 4 + (tid >> 6);
        int l = tid & 63;
        const float* gw = gate_w + (size_t)d * D_;
        float p = 0.f;
#pragma unroll
        for (int i = 0; i < 8; ++i) p += gw[l + 64 * i] * sp_b[l + 64 * i];
#pragma unroll
        for (int off = 32; off > 0; off >>= 1) p += __shfl_xor(p, off);
        if (l == 0) Mb[d] = p + gate_b[d];
        float acc = 0.f;
        for (int k = 0; k < D_; k += 4) {
            float4 a4 = *(const float4*)&gw[k];
            acc += a4.x * sp_w[(k + 0) * HD_ + l] + a4.y * sp_w[(k + 1) * HD_ + l] +
                   a4.z * sp_w[(k + 2) * HD_ + l] + a4.w * sp_w[(k + 3) * HD_ + l];
        }
        MT[(size_t)l * D_ + d] = acc;
    }
}

// ---------- k2: gate = sigmoid(hd @ M^T + Mb) ; K = 64, no LDS
__global__ __launch_bounds__(256) void k_gate(const float* __restrict__ hd_g,
                                              const float* __restrict__ MT,
                                              const float* __restrict__ Mb,
                                              float* __restrict__ gate) {
    int bid = blockIdx.x, tid = threadIdx.x;
    int t0 = (bid >> 3) * 8, c0 = (bid & 7) * 64;
    int rr = tid >> 6, c = tid & 63;
    int ta = t0 + rr, tb = t0 + rr + 4;
    const float4* hd4 = (const float4*)hd_g;
    float acc0 = 0.f, acc1 = 0.f;
#pragma unroll
    for (int j4 = 0; j4 < 16; ++j4) {
        float4 h0 = hd4[ta * 16 + j4];
        float4 h1 = hd4[tb * 16 + j4];
        int j = j4 * 4;
        float m0 = MT[(size_t)(j + 0) * D_ + c0 + c];
        float m1 = MT[(size_t)(j + 1) * D_ + c0 + c];
        float m2 = MT[(size_t)(j + 2) * D_ + c0 + c];
        float m3 = MT[(size_t)(j + 3) * D_ + c0 + c];
        acc0 += h0.x * m0 + h0.y * m1 + h0.z * m2 + h0.w * m3;
        acc1 += h1.x * m0 + h1.y * m1 + h1.z * m2 + h1.w * m3;
    }
    float mb = Mb[c0 + c];
    gate[(size_t)ta * D_ + c0 + c] = 1.f / (1.f + expf(-(acc0 + mb)));
    gate[(size_t)tb * D_ + c0 + c] = 1.f / (1.f + expf(-(acc1 + mb)));
}

// ---------- k3: scores Gram partials (no sqrt): 64x64 x 64K tiles, z = b*8+ks
__global__ __launch_bounds__(256) void k_scores_part(const float* __restrict__ gate,
                                                     float* __restrict__ spart) {
    int z = blockIdx.z;
    int b = z >> 3, ks = z & 7;
    int kbase = ks * 64;
    int i0 = blockIdx.y * 64, j0 = blockIdx.x * 64;
    int tid = threadIdx.x;
    int tx = tid & 15, ty = tid >> 4;
    __shared__ float Ash[16][68];
    __shared__ float Bsh[16][68];
    float acc[4][4];
#pragma unroll
    for (int r = 0; r < 4; ++r)
#pragma unroll
        for (int c = 0; c < 4; ++c) acc[r][c] = 0.f;
    const float* gb = gate + (size_t)b * T_ * D_;
    int sr = tid >> 2, sc4 = (tid & 3) * 4;
    for (int k0 = kbase; k0 < kbase + 64; k0 += 16) {
        float4 av = *(const float4*)&gb[(size_t)(i0 + sr) * D_ + k0 + sc4];
        float4 bvv = *(const float4*)&gb[(size_t)(j0 + sr) * D_ + k0 + sc4];
        Ash[sc4 + 0][sr] = av.x * av.x;
        Ash[sc4 + 1][sr] = av.y * av.y;
        Ash[sc4 + 2][sr] = av.z * av.z;
        Ash[sc4 + 3][sr] = av.w * av.w;
        Bsh[sc4 + 0][sr] = bvv.x * bvv.x;
        Bsh[sc4 + 1][sr] = bvv.y * bvv.y;
        Bsh[sc4 + 2][sr] = bvv.z * bvv.z;
        Bsh[sc4 + 3][sr] = bvv.w * bvv.w;
        __syncthreads();
#pragma unroll
        for (int kk = 0; kk < 16; ++kk) {
            float4 a4 = *(const float4*)&Ash[kk][4 * ty];
            float4 b4 = *(const float4*)&Bsh[kk][4 * tx];
            float ar[4] = {a4.x, a4.y, a4.z, a4.w};
            float bc[4] = {b4.x, b4.y, b4.z, b4.w};
#pragma unroll
            for (int r = 0; r < 4; ++r)
#pragma unroll
                for (int c = 0; c < 4; ++c) acc[r][c] += ar[r] * bc[c];
        }
        __syncthreads();
    }
    float* sp = spart + (size_t)z * T2;
#pragma unroll
    for (int r = 0; r < 4; ++r) {
        float4 o;
        o.x = acc[r][0];
        o.y = acc[r][1];
        o.z = acc[r][2];
        o.w = acc[r][3];
        *(float4*)&sp[(size_t)(i0 + 4 * ty + r) * T_ + j0 + 4 * tx] = o;
    }
}

// ---------- k4: rank-based top-K + entangle, 1 row / block, 256 threads
__global__ __launch_bounds__(256) void k_topk_ent(const float* __restrict__ spart,
                                                  const float* __restrict__ gate,
                                                  const float* __restrict__ xs,
                                                  float* __restrict__ xo) {
    __shared__ float s[T_];
    __shared__ int sel[K_];
    int row = blockIdx.x, tid = threadIdx.x;
    int b = row / T_;
    int i = row - b * T_;
    for (int j = tid; j < T_; j += 256) {
        float acc = 0.f;
#pragma unroll
        for (int ks = 0; ks < 8; ++ks)
            acc += spart[(size_t)(b * 8 + ks) * T2 + (size_t)i * T_ + j];
        s[j] = acc;
    }
    __syncthreads();
    for (int j = tid; j < T_; j += 256) {
        float v = s[j];
        int cnt = 0;
        for (int j2 = 0; j2 < T_; ++j2) {
            float u = s[j2];
            cnt += (u > v) || (u == v && j2 < j);
        }
        if (cnt < K_) sel[cnt] = j;
    }
    __syncthreads();
    const float2* g2 = (const float2*)gate;
    float2 sum = {0.f, 0.f};
    int rb = b * T_;
    for (int n = 0; n < K_; ++n) {
        int j = sel[n];
        float2 g = g2[(size_t)(rb + j) * 256 + tid];
        sum.x += g.x;
        sum.y += g.y;
    }
    float2 gi = g2[(size_t)row * 256 + tid];
    float2 xv = ((const float2*)xs)[(size_t)row * 256 + tid];
    float2 o;
    o.x = xv.x + gi.x * sum.x;
    o.y = xv.y + gi.y * sum.y;
    ((float2*)xo)[(size_t)row * 256 + tid] = o;
}

// ---------- k5: U GEMM partials + last-block LN fixup (split-K pattern)
// grid (8, 24, 4) = 768 blocks; 32 blocks contribute per 32-row tile.
// The 32nd arriver (agent-scope atomic) reduces 4 partials + bias + LayerNorm
// for its 32 rows — wave-per-row, barrier-free tail. Deterministic: fixed q
// read order.
__global__ __launch_bounds__(256) void k_wgemm_ln(
    const float* __restrict__ in, const float* __restrict__ W,
    const float* __restrict__ U_b, const float* __restrict__ ln_g,
    const float* __restrict__ ln_b, float* __restrict__ part,
    float* __restrict__ out) {
    int c0 = blockIdx.x * 64, r0 = blockIdx.y * 32;
    int kbase = blockIdx.z * 128;
    float* pout = part + (size_t)blockIdx.z * PSTRIDE;
    int tid = threadIdx.x;
    int ry = tid >> 4, cx = tid & 15;
    __shared__ float A_shT[32][33];
    __shared__ float B_sh[32][65];
    float acc[2][4];
#pragma unroll
    for (int r = 0; r < 2; ++r)
#pragma unroll
        for (int c = 0; c < 4; ++c) acc[r][c] = 0.f;
    int asr = tid >> 3, asc = (tid & 7) * 4;
    int bsr = tid >> 2, bsk = (tid & 3) * 8;
    for (int k0 = kbase; k0 < kbase + 128; k0 += 32) {
        float4 a4 = *(const float4*)&in[(size_t)(r0 + asr) * D_ + k0 + asc];
        A_shT[asc + 0][asr] = a4.x;
        A_shT[asc + 1][asr] = a4.y;
        A_shT[asc + 2][asr] = a4.z;
        A_shT[asc + 3][asr] = a4.w;
        float4 b4a = *(const float4*)&W[(size_t)(c0 + bsr) * D_ + k0 + bsk];
        float4 b4b = *(const float4*)&W[(size_t)(c0 + bsr) * D_ + k0 + bsk + 4];
        B_sh[bsk + 0][bsr] = b4a.x;
        B_sh[bsk + 1][bsr] = b4a.y;
        B_sh[bsk + 2][bsr] = b4a.z;
        B_sh[bsk + 3][bsr] = b4a.w;
        B_sh[bsk + 4][bsr] = b4b.x;
        B_sh[bsk + 5][bsr] = b4b.y;
        B_sh[bsk + 6][bsr] = b4b.z;
        B_sh[bsk + 7][bsr] = b4b.w;
        __syncthreads();
#pragma unroll
        for (int kk = 0; kk < 32; ++kk) {
            float2 a2 = *(const float2*)&A_shT[kk][ry * 2];
            float4 b4 = *(const float4*)&B_sh[kk][cx * 4];
            acc[0][0] += a2.x * b4.x; acc[0][1] += a2.x * b4.y;
            acc[0][2] += a2.x * b4.z; acc[0][3] += a2.x * b4.w;
            acc[1][0] += a2.y * b4.x; acc[1][1] += a2.y * b4.y;
            acc[1][2] += a2.y * b4.z; acc[1][3] += a2.y * b4.w;
        }
        __syncthreads();
    }
#pragma unroll
    for (int r = 0; r < 2; ++r) {
        float4 o;
        o.x = acc[r][0];
        o.y = acc[r][1];
        o.z = acc[r][2];
        o.w = acc[r][3];
        *(float4*)&pout[(size_t)(r0 + ry * 2 + r) * D_ + c0 + cx * 4] = o;
    }
    // ---- completion protocol (no spinning; classic threadfence reduction) ----
    __threadfence();
    __syncthreads();
    __shared__ int isLast;
    if (tid == 0) {
        unsigned t = __hip_atomic_fetch_add(&g_ctr[blockIdx.y], 1u,
                                            __ATOMIC_ACQ_REL, __HIP_MEMORY_SCOPE_AGENT);
        isLast = ((t & 31u) == 31u);
    }
    __syncthreads();
    if (!isLast) return;
    __threadfence();  // acquire side: ensure others' partials visible
    // ---- LN tail: rows r0..r0+31, wave per row, 8 groups of 4 rows ----
    int lane = tid & 63, wv = tid >> 6;
    const float4* p4 = (const float4*)part;
    const float4* ub4 = (const float4*)U_b;
    const float4* lg4 = (const float4*)ln_g;
    const float4* lb4 = (const float4*)ln_b;
    float4* out4 = (float4*)out;
    for (int g = 0; g < 8; ++g) {
        int r = r0 + g * 4 + wv;
        size_t base = (size_t)r * (D_ / 4) + lane * 2;
        float4 s0 = {0.f, 0.f, 0.f, 0.f}, s1 = {0.f, 0.f, 0.f, 0.f};
#pragma unroll
        for (int q = 0; q < 4; ++q) {
            float4 a = p4[base + (size_t)q * (PSTRIDE / 4)];
            float4 bq = p4[base + 1 + (size_t)q * (PSTRIDE / 4)];
            s0.x += a.x;  s0.y += a.y;  s0.z += a.z;  s0.w += a.w;
            s1.x += bq.x; s1.y += bq.y; s1.z += bq.z; s1.w += bq.w;
        }
        float4 u0 = ub4[lane * 2], u1 = ub4[lane * 2 + 1];
        s0.x += u0.x; s0.y += u0.y; s0.z += u0.z; s0.w += u0.w;
        s1.x += u1.x; s1.y += u1.y; s1.z += u1.z; s1.w += u1.w;
        float sum = s0.x + s0.y + s0.z + s0.w + s1.x + s1.y + s1.z + s1.w;
        float sq = s0.x * s0.x + s0.y * s0.y + s0.z * s0.z + s0.w * s0.w +
                   s1.x * s1.x + s1.y * s1.y + s1.z * s1.z + s1.w * s1.w;
#pragma unroll
        for (int off = 32; off > 0; off >>= 1) {
            sum += __shfl_xor(sum, off);
            sq += __shfl_xor(sq, off);
        }
        float mu = sum * (1.f / D_);
        float var = fmaxf(sq * (1.f / D_) - mu * mu, 0.f);
        float inv = rsqrtf(var + LN_EPS);
        float4 g0 = lg4[lane * 2], g1 = lg4[lane * 2 + 1];
        float4 b0 = lb4[lane * 2], b1 = lb4[lane * 2 + 1];
        float4 o0, o1;
        o0.x = g0.x * (s0.x - mu) * inv + b0.x;
        o0.y = g0.y * (s0.y - mu) * inv + b0.y;
        o0.z = g0.z * (s0.z - mu) * inv + b0.z;
        o0.w = g0.w * (s0.w - mu) * inv + b0.w;
        o1.x = g1.x * (s1.x - mu) * inv + b1.x;
        o1.y = g1.y * (s1.y - mu) * inv + b1.y;
        o1.z = g1.z * (s1.z - mu) * inv + b1.z;
        o1.w = g1.w * (s1.w - mu) * inv + b1.w;
        out4[base] = o0;
        out4[base + 1] = o1;
    }
}

// --------------------------------------------------------------------- launch
extern "C" void kernel_launch(void* const* d_in, const int* in_sizes, int n_in,
                              void* d_out, int out_size, void* d_ws, size_t ws_size,
                              hipStream_t stream) {
    const float* x      = (const float*)d_in[0];
    const float* g_w    = (const float*)d_in[1];
    const float* g_b    = (const float*)d_in[2];
    const float* sp_w   = (const float*)d_in[3];
    const float* sp_b   = (const float*)d_in[4];
    const float* gate_w = (const float*)d_in[5];
    const float* gate_b = (const float*)d_in[6];
    const float* U_w    = (const float*)d_in[7];
    const float* U_b    = (const float*)d_in[8];
    const float* ln_g   = (const float*)d_in[9];
    const float* ln_b   = (const float*)d_in[10];

    float* ws    = (float*)d_ws;
    float* xs    = ws;                   // 393216
    float* gate  = xs + PSTRIDE;         // 393216
    float* xo    = gate + PSTRIDE;       // 393216
    float* hd_g  = xo + PSTRIDE;         // 49152
    float* MT    = hd_g + 49152;         // 32768
    float* Mb    = MT + 32768;           // 512
    float* part  = Mb + 512;             // 4 * 393216
    float* spart = part + 4 * PSTRIDE;   // 16 * 147456

    k_super_m<<<NTOK + 128, 256, 0, stream>>>(x, g_w, g_b, sp_w, sp_b, gate_w,
                                              gate_b, xs, hd_g, MT, Mb);
    k_gate<<<NTOK, 256, 0, stream>>>(hd_g, MT, Mb, gate);
    k_scores_part<<<dim3(T_ / 64, T_ / 64, 16), 256, 0, stream>>>(gate, spart);
    k_topk_ent<<<NTOK, 256, 0, stream>>>(spart, gate, xs, xo);
    k_wgemm_ln<<<dim3(D_ / 64, NTOK / 32, 4), 256, 0, stream>>>(
        xo, U_w, U_b, ln_g, ln_b, part, (float*)d_out);
}